// Round 1
// baseline (4593.876 us; speedup 1.0000x reference)
//
#include <hip/hip_runtime.h>

// Problem constants (match reference)
#define NN 100000   // nodes
#define NE 400000   // edges per relation
#define NR 3        // relations
#define DD 128      // feature dim

// ws layout (floats):
//   agg : NR*NN*DD   = 38,400,000   (153.6 MB)
//   h1  : NN*DD      = 12,800,000   ( 51.2 MB)
//   cnt : NR*NN      =    300,000
//   inv : NR*NN      =    300,000
// total = 207.2 MB

__global__ __launch_bounds__(256) void gnn_count(const int* __restrict__ ei,
                                                 float* __restrict__ cnt) {
    int t = blockIdx.x * 256 + threadIdx.x;
    if (t >= NR * NE) return;
    int r = t / NE;
    int e = t - r * NE;
    int dst = ei[(r * 2 + 1) * NE + e];
    atomicAdd(&cnt[r * NN + dst], 1.0f);
}

__global__ __launch_bounds__(256) void gnn_inv(const float* __restrict__ cnt,
                                               float* __restrict__ inv) {
    int t = blockIdx.x * 256 + threadIdx.x;
    if (t >= NR * NN) return;
    inv[t] = 1.0f / fmaxf(cnt[t], 1.0f);
}

// One 32-lane group per (relation, edge): gather 512B row of h[src], atomic-add into agg[r][dst].
__global__ __launch_bounds__(256) void gnn_scatter(const float* __restrict__ h,
                                                   const int* __restrict__ ei,
                                                   float* __restrict__ agg) {
    int t = blockIdx.x * 256 + threadIdx.x;   // max 38.4M, fits int
    int gid = t >> 5;                          // edge slot in [0, NR*NE) -- exact grid
    int lane = t & 31;
    int r = gid / NE;
    int e = gid - r * NE;
    int src = ei[(r * 2 + 0) * NE + e];
    int dst = ei[(r * 2 + 1) * NE + e];
    float4 v = *reinterpret_cast<const float4*>(h + (size_t)src * DD + lane * 4);
    float* a = agg + ((size_t)r * NN + dst) * DD + lane * 4;
    atomicAdd(a + 0, v.x);
    atomicAdd(a + 1, v.y);
    atomicAdd(a + 2, v.z);
    atomicAdd(a + 3, v.w);
}

// Fused per-layer GEMM: out = [agg0*inv0 | agg1*inv1 | agg2*inv2 | h] @ [Wn0;Wn1;Wn2;sum(Wr)] + sum(b)
// BM=64 rows x BN=128 cols per block, K=512 in 16 slabs of 32.
// FINAL: fuse classifier (@Wc + bc) via 32-lane shuffle reduce.
template <int RELU, int FINAL>
__global__ __launch_bounds__(256) void gnn_gemm(
    const float* __restrict__ agg, const float* __restrict__ inv,
    const float* __restrict__ h,
    const float* __restrict__ Wn,   // layer base: [3][128][128]
    const float* __restrict__ Wr,   // layer base: [3][128][128]
    const float* __restrict__ bb,   // layer base: [3][128]
    const float* __restrict__ Wc,   // [128][2] (FINAL only)
    const float* __restrict__ bc,   // [2]      (FINAL only)
    float* __restrict__ out)        // h1 [NN][128] or logits [NN][2]
{
    __shared__ float As[64 * 36];     // stride 36: 16B-aligned rows, bank-rotating
    __shared__ float Wsh[32 * 128];
    const int m0 = blockIdx.x * 64;
    const int t = threadIdx.x;
    const int tx = t & 31;            // col group: cols tx*4..tx*4+3
    const int ty = t >> 5;            // row group: rows ty*8..ty*8+7
    float acc[8][4] = {};

    for (int s = 0; s < 16; ++s) {
        const int srcid = s >> 2;        // 0..2 = agg relation, 3 = root (h)
        const int k0 = (s & 3) * 32;
        // ---- A tile: 64 rows x 32 k  (512 float4, 2 per thread) ----
        #pragma unroll
        for (int i0 = 0; i0 < 2; ++i0) {
            int i = t + i0 * 256;
            int row = i >> 3;
            int c4 = i & 7;
            int grow = m0 + row;
            if (grow > NN - 1) grow = NN - 1;   // clamp; stores are guarded
            float4 v;
            if (srcid < 3) {
                v = *reinterpret_cast<const float4*>(
                    agg + ((size_t)srcid * NN + grow) * DD + k0 + c4 * 4);
                float sc = inv[srcid * NN + grow];
                v.x *= sc; v.y *= sc; v.z *= sc; v.w *= sc;
            } else {
                v = *reinterpret_cast<const float4*>(h + (size_t)grow * DD + k0 + c4 * 4);
            }
            *reinterpret_cast<float4*>(&As[row * 36 + c4 * 4]) = v;
        }
        // ---- W tile: 32 k x 128 cols (1024 float4, 4 per thread) ----
        #pragma unroll
        for (int i0 = 0; i0 < 4; ++i0) {
            int i = t + i0 * 256;
            int kk = i >> 5;
            int c4 = i & 31;
            int krow = k0 + kk;
            float4 v;
            if (srcid < 3) {
                v = *reinterpret_cast<const float4*>(
                    Wn + ((size_t)srcid * DD + krow) * DD + c4 * 4);
            } else {
                float4 v0 = *reinterpret_cast<const float4*>(Wr + ((size_t)0 * DD + krow) * DD + c4 * 4);
                float4 v1 = *reinterpret_cast<const float4*>(Wr + ((size_t)1 * DD + krow) * DD + c4 * 4);
                float4 v2 = *reinterpret_cast<const float4*>(Wr + ((size_t)2 * DD + krow) * DD + c4 * 4);
                v.x = v0.x + v1.x + v2.x;
                v.y = v0.y + v1.y + v2.y;
                v.z = v0.z + v1.z + v2.z;
                v.w = v0.w + v1.w + v2.w;
            }
            *reinterpret_cast<float4*>(&Wsh[kk * 128 + c4 * 4]) = v;
        }
        __syncthreads();
        #pragma unroll 8
        for (int kk = 0; kk < 32; ++kk) {
            float4 wv = *reinterpret_cast<const float4*>(&Wsh[kk * 128 + tx * 4]);
            #pragma unroll
            for (int rr = 0; rr < 8; ++rr) {
                float a = As[(ty * 8 + rr) * 36 + kk];   // broadcast within half-wave
                acc[rr][0] = fmaf(a, wv.x, acc[rr][0]);
                acc[rr][1] = fmaf(a, wv.y, acc[rr][1]);
                acc[rr][2] = fmaf(a, wv.z, acc[rr][2]);
                acc[rr][3] = fmaf(a, wv.w, acc[rr][3]);
            }
        }
        __syncthreads();
    }

    const int col = tx * 4;
    float bias[4];
    #pragma unroll
    for (int j = 0; j < 4; ++j)
        bias[j] = bb[col + j] + bb[DD + col + j] + bb[2 * DD + col + j];

    if (!FINAL) {
        #pragma unroll
        for (int rr = 0; rr < 8; ++rr) {
            int row = m0 + ty * 8 + rr;
            if (row < NN) {
                float4 o;
                o.x = acc[rr][0] + bias[0];
                o.y = acc[rr][1] + bias[1];
                o.z = acc[rr][2] + bias[2];
                o.w = acc[rr][3] + bias[3];
                if (RELU) {
                    o.x = fmaxf(o.x, 0.f); o.y = fmaxf(o.y, 0.f);
                    o.z = fmaxf(o.z, 0.f); o.w = fmaxf(o.w, 0.f);
                }
                *reinterpret_cast<float4*>(out + (size_t)row * DD + col) = o;
            }
        }
    } else {
        float wc0[4], wc1[4];
        #pragma unroll
        for (int j = 0; j < 4; ++j) {
            wc0[j] = Wc[(col + j) * 2 + 0];
            wc1[j] = Wc[(col + j) * 2 + 1];
        }
        #pragma unroll
        for (int rr = 0; rr < 8; ++rr) {
            float p0 = 0.f, p1 = 0.f;
            #pragma unroll
            for (int j = 0; j < 4; ++j) {
                float v = acc[rr][j] + bias[j];
                p0 = fmaf(v, wc0[j], p0);
                p1 = fmaf(v, wc1[j], p1);
            }
            #pragma unroll
            for (int off = 1; off < 32; off <<= 1) {   // xor<32 stays in 32-lane half
                p0 += __shfl_xor(p0, off);
                p1 += __shfl_xor(p1, off);
            }
            int row = m0 + ty * 8 + rr;
            if (tx == 0 && row < NN) {
                out[(size_t)row * 2 + 0] = p0 + bc[0];
                out[(size_t)row * 2 + 1] = p1 + bc[1];
            }
        }
    }
}

extern "C" void kernel_launch(void* const* d_in, const int* in_sizes, int n_in,
                              void* d_out, int out_size, void* d_ws, size_t ws_size,
                              hipStream_t stream) {
    const float* x  = (const float*)d_in[0];   // [NN][128]
    const int*   ei = (const int*)d_in[1];     // [3][2][NE]
    const float* Wn = (const float*)d_in[2];   // [2][3][128][128]
    const float* Wr = (const float*)d_in[3];   // [2][3][128][128]
    const float* b  = (const float*)d_in[4];   // [2][3][128]
    const float* Wc = (const float*)d_in[5];   // [128][2]
    const float* bc = (const float*)d_in[6];   // [2]
    float* out = (float*)d_out;                // [NN][2]

    float* agg = (float*)d_ws;                           // NR*NN*DD
    float* h1  = agg + (size_t)NR * NN * DD;             // NN*DD
    float* cnt = h1 + (size_t)NN * DD;                   // NR*NN
    float* inv = cnt + (size_t)NR * NN;                  // NR*NN

    const size_t aggBytes = (size_t)NR * NN * DD * sizeof(float);

    hipMemsetAsync(agg, 0, aggBytes, stream);
    hipMemsetAsync(cnt, 0, (size_t)NR * NN * sizeof(float), stream);

    gnn_count<<<(NR * NE + 255) / 256, 256, 0, stream>>>(ei, cnt);
    gnn_inv<<<(NR * NN + 255) / 256, 256, 0, stream>>>(cnt, inv);

    const int scatterBlocks = NR * NE * 32 / 256;   // exact: 150000
    const int gemmBlocks = (NN + 63) / 64;          // 1563

    // Layer 0: h1 = relu( sum_r mean_r(x) @ Wn[0,r] + x @ sum_r Wr[0,r] + sum_r b[0,r] )
    gnn_scatter<<<scatterBlocks, 256, 0, stream>>>(x, ei, agg);
    gnn_gemm<1, 0><<<gemmBlocks, 256, 0, stream>>>(agg, inv, x,
                                                   Wn, Wr, b, nullptr, nullptr, h1);

    // Layer 1 (+ fused classifier)
    hipMemsetAsync(agg, 0, aggBytes, stream);
    gnn_scatter<<<scatterBlocks, 256, 0, stream>>>(h1, ei, agg);
    gnn_gemm<0, 1><<<gemmBlocks, 256, 0, stream>>>(agg, inv, h1,
                                                   Wn + (size_t)NR * DD * DD,
                                                   Wr + (size_t)NR * DD * DD,
                                                   b + (size_t)NR * DD,
                                                   Wc, bc, out);
}

// Round 2
// 895.360 us; speedup vs baseline: 5.1308x; 5.1308x over previous
//
#include <hip/hip_runtime.h>

// Problem constants (match reference)
#define NN 100000   // nodes
#define NE 400000   // edges per relation
#define NR 3        // relations
#define DD 128      // feature dim
#define NROWS (NR * NN)          // 300000 CSR rows
#define NEDGES (NR * NE)         // 1200000 edges total
#define SCAN_BLOCKS ((NROWS + 1023) / 1024)   // 293

// ws layout:
//   agg       : NR*NN*DD floats = 153.6 MB   (written fully by gather, no memset)
//   h1        : NN*DD floats    =  51.2 MB
//   bucket    : NEDGES ints     =   4.8 MB
//   cnt       : NROWS ints
//   row_start : NROWS ints
//   cursor    : NROWS ints
//   bsum      : 512 ints
// total ~212 MB

// ---------- CSR build ----------
__global__ __launch_bounds__(256) void csr_count(const int* __restrict__ ei,
                                                 int* __restrict__ cnt) {
    int t = blockIdx.x * 256 + threadIdx.x;
    if (t >= NEDGES) return;
    int r = t / NE;
    int e = t - r * NE;
    int dst = ei[(r * 2 + 1) * NE + e];
    atomicAdd(&cnt[r * NN + dst], 1);
}

// block-local exclusive scan: 256 threads x 4 elems = 1024/block
__global__ __launch_bounds__(256) void scan1(const int* __restrict__ cnt,
                                             int* __restrict__ row_start,
                                             int* __restrict__ bsum) {
    __shared__ int sh[256];
    int b0 = blockIdx.x * 1024;
    int t = threadIdx.x;
    int v[4];
    int s = 0;
    #pragma unroll
    for (int j = 0; j < 4; ++j) {
        int idx = b0 + t * 4 + j;
        v[j] = (idx < NROWS) ? cnt[idx] : 0;
        s += v[j];
    }
    sh[t] = s;
    __syncthreads();
    for (int off = 1; off < 256; off <<= 1) {
        int val = (t >= off) ? sh[t - off] : 0;
        __syncthreads();
        sh[t] += val;
        __syncthreads();
    }
    int excl = (t == 0) ? 0 : sh[t - 1];
    if (t == 255) bsum[blockIdx.x] = sh[255];
    #pragma unroll
    for (int j = 0; j < 4; ++j) {
        int idx = b0 + t * 4 + j;
        if (idx < NROWS) { row_start[idx] = excl; excl += v[j]; }
    }
}

__global__ __launch_bounds__(512) void scan2(int* __restrict__ bsum, int nb) {
    __shared__ int sh[512];
    int t = threadIdx.x;
    sh[t] = (t < nb) ? bsum[t] : 0;
    __syncthreads();
    for (int off = 1; off < 512; off <<= 1) {
        int val = (t >= off) ? sh[t - off] : 0;
        __syncthreads();
        sh[t] += val;
        __syncthreads();
    }
    int excl = (t == 0) ? 0 : sh[t - 1];
    if (t < nb) bsum[t] = excl;
}

__global__ __launch_bounds__(256) void scan3(int* __restrict__ row_start,
                                             const int* __restrict__ bsum) {
    int idx = blockIdx.x * 256 + threadIdx.x;
    if (idx < NROWS) row_start[idx] += bsum[idx >> 10];
}

__global__ __launch_bounds__(256) void csr_fill(const int* __restrict__ ei,
                                                const int* __restrict__ row_start,
                                                int* __restrict__ cursor,
                                                int* __restrict__ bucket) {
    int t = blockIdx.x * 256 + threadIdx.x;
    if (t >= NEDGES) return;
    int r = t / NE;
    int e = t - r * NE;
    int src = ei[(r * 2 + 0) * NE + e];
    int dst = ei[(r * 2 + 1) * NE + e];
    int i = r * NN + dst;
    int pos = row_start[i] + atomicAdd(&cursor[i], 1);
    bucket[pos] = src;
}

// ---------- aggregation: one 64-lane wave per (relation, dst) row ----------
__global__ __launch_bounds__(256) void gnn_gather(const float* __restrict__ h,
                                                  const int* __restrict__ bucket,
                                                  const int* __restrict__ row_start,
                                                  const int* __restrict__ cnt,
                                                  float* __restrict__ agg) {
    int wid = (blockIdx.x * 256 + threadIdx.x) >> 6;   // CSR row
    int lane = threadIdx.x & 63;
    if (wid >= NROWS) return;
    int base = row_start[wid];
    int deg = cnt[wid];
    float2 acc = {0.f, 0.f};
    for (int e = 0; e < deg; ++e) {
        int src = bucket[base + e];                     // wave-uniform load
        float2 v = *reinterpret_cast<const float2*>(h + (size_t)src * DD + lane * 2);
        acc.x += v.x;
        acc.y += v.y;
    }
    float sc = (deg > 0) ? (1.0f / (float)deg) : 0.0f;  // deg=0 -> row stays 0
    acc.x *= sc;
    acc.y *= sc;
    *reinterpret_cast<float2*>(agg + (size_t)wid * DD + lane * 2) = acc;
}

// ---------- fused per-layer GEMM ----------
// out = [agg0 | agg1 | agg2 | h] @ [Wn0;Wn1;Wn2;sum(Wr)] + sum(b)   (agg pre-divided)
// BM=64 x BN=128, K=512 in 16 slabs of 32. FINAL fuses classifier via shuffle reduce.
template <int RELU, int FINAL>
__global__ __launch_bounds__(256) void gnn_gemm(
    const float* __restrict__ agg,
    const float* __restrict__ h,
    const float* __restrict__ Wn,   // layer base: [3][128][128]
    const float* __restrict__ Wr,   // layer base: [3][128][128]
    const float* __restrict__ bb,   // layer base: [3][128]
    const float* __restrict__ Wc,   // [128][2] (FINAL only)
    const float* __restrict__ bc,   // [2]      (FINAL only)
    float* __restrict__ out)        // h1 [NN][128] or logits [NN][2]
{
    __shared__ float As[64 * 36];
    __shared__ float Wsh[32 * 128];
    const int m0 = blockIdx.x * 64;
    const int t = threadIdx.x;
    const int tx = t & 31;
    const int ty = t >> 5;
    float acc[8][4] = {};

    for (int s = 0; s < 16; ++s) {
        const int srcid = s >> 2;        // 0..2 = agg relation, 3 = root (h)
        const int k0 = (s & 3) * 32;
        #pragma unroll
        for (int i0 = 0; i0 < 2; ++i0) {
            int i = t + i0 * 256;
            int row = i >> 3;
            int c4 = i & 7;
            int grow = m0 + row;
            if (grow > NN - 1) grow = NN - 1;
            float4 v;
            if (srcid < 3) {
                v = *reinterpret_cast<const float4*>(
                    agg + ((size_t)srcid * NN + grow) * DD + k0 + c4 * 4);
            } else {
                v = *reinterpret_cast<const float4*>(h + (size_t)grow * DD + k0 + c4 * 4);
            }
            *reinterpret_cast<float4*>(&As[row * 36 + c4 * 4]) = v;
        }
        #pragma unroll
        for (int i0 = 0; i0 < 4; ++i0) {
            int i = t + i0 * 256;
            int kk = i >> 5;
            int c4 = i & 31;
            int krow = k0 + kk;
            float4 v;
            if (srcid < 3) {
                v = *reinterpret_cast<const float4*>(
                    Wn + ((size_t)srcid * DD + krow) * DD + c4 * 4);
            } else {
                float4 v0 = *reinterpret_cast<const float4*>(Wr + ((size_t)0 * DD + krow) * DD + c4 * 4);
                float4 v1 = *reinterpret_cast<const float4*>(Wr + ((size_t)1 * DD + krow) * DD + c4 * 4);
                float4 v2 = *reinterpret_cast<const float4*>(Wr + ((size_t)2 * DD + krow) * DD + c4 * 4);
                v.x = v0.x + v1.x + v2.x;
                v.y = v0.y + v1.y + v2.y;
                v.z = v0.z + v1.z + v2.z;
                v.w = v0.w + v1.w + v2.w;
            }
            *reinterpret_cast<float4*>(&Wsh[kk * 128 + c4 * 4]) = v;
        }
        __syncthreads();
        #pragma unroll 8
        for (int kk = 0; kk < 32; ++kk) {
            float4 wv = *reinterpret_cast<const float4*>(&Wsh[kk * 128 + tx * 4]);
            #pragma unroll
            for (int rr = 0; rr < 8; ++rr) {
                float a = As[(ty * 8 + rr) * 36 + kk];
                acc[rr][0] = fmaf(a, wv.x, acc[rr][0]);
                acc[rr][1] = fmaf(a, wv.y, acc[rr][1]);
                acc[rr][2] = fmaf(a, wv.z, acc[rr][2]);
                acc[rr][3] = fmaf(a, wv.w, acc[rr][3]);
            }
        }
        __syncthreads();
    }

    const int col = tx * 4;
    float bias[4];
    #pragma unroll
    for (int j = 0; j < 4; ++j)
        bias[j] = bb[col + j] + bb[DD + col + j] + bb[2 * DD + col + j];

    if (!FINAL) {
        #pragma unroll
        for (int rr = 0; rr < 8; ++rr) {
            int row = m0 + ty * 8 + rr;
            if (row < NN) {
                float4 o;
                o.x = acc[rr][0] + bias[0];
                o.y = acc[rr][1] + bias[1];
                o.z = acc[rr][2] + bias[2];
                o.w = acc[rr][3] + bias[3];
                if (RELU) {
                    o.x = fmaxf(o.x, 0.f); o.y = fmaxf(o.y, 0.f);
                    o.z = fmaxf(o.z, 0.f); o.w = fmaxf(o.w, 0.f);
                }
                *reinterpret_cast<float4*>(out + (size_t)row * DD + col) = o;
            }
        }
    } else {
        float wc0[4], wc1[4];
        #pragma unroll
        for (int j = 0; j < 4; ++j) {
            wc0[j] = Wc[(col + j) * 2 + 0];
            wc1[j] = Wc[(col + j) * 2 + 1];
        }
        #pragma unroll
        for (int rr = 0; rr < 8; ++rr) {
            float p0 = 0.f, p1 = 0.f;
            #pragma unroll
            for (int j = 0; j < 4; ++j) {
                float v = acc[rr][j] + bias[j];
                p0 = fmaf(v, wc0[j], p0);
                p1 = fmaf(v, wc1[j], p1);
            }
            #pragma unroll
            for (int off = 1; off < 32; off <<= 1) {
                p0 += __shfl_xor(p0, off);
                p1 += __shfl_xor(p1, off);
            }
            int row = m0 + ty * 8 + rr;
            if (tx == 0 && row < NN) {
                out[(size_t)row * 2 + 0] = p0 + bc[0];
                out[(size_t)row * 2 + 1] = p1 + bc[1];
            }
        }
    }
}

extern "C" void kernel_launch(void* const* d_in, const int* in_sizes, int n_in,
                              void* d_out, int out_size, void* d_ws, size_t ws_size,
                              hipStream_t stream) {
    const float* x  = (const float*)d_in[0];   // [NN][128]
    const int*   ei = (const int*)d_in[1];     // [3][2][NE]
    const float* Wn = (const float*)d_in[2];   // [2][3][128][128]
    const float* Wr = (const float*)d_in[3];   // [2][3][128][128]
    const float* b  = (const float*)d_in[4];   // [2][3][128]
    const float* Wc = (const float*)d_in[5];   // [128][2]
    const float* bc = (const float*)d_in[6];   // [2]
    float* out = (float*)d_out;                // [NN][2]

    float* agg       = (float*)d_ws;                          // NR*NN*DD
    float* h1        = agg + (size_t)NR * NN * DD;            // NN*DD
    int*   bucket    = (int*)(h1 + (size_t)NN * DD);          // NEDGES
    int*   cnt       = bucket + NEDGES;                       // NROWS
    int*   row_start = cnt + NROWS;                           // NROWS
    int*   cursor    = row_start + NROWS;                     // NROWS
    int*   bsum      = cursor + NROWS;                        // 512

    // ---- build CSR (shared by both layers) ----
    hipMemsetAsync(cnt, 0, NROWS * sizeof(int), stream);
    hipMemsetAsync(cursor, 0, NROWS * sizeof(int), stream);
    csr_count<<<(NEDGES + 255) / 256, 256, 0, stream>>>(ei, cnt);
    scan1<<<SCAN_BLOCKS, 256, 0, stream>>>(cnt, row_start, bsum);
    scan2<<<1, 512, 0, stream>>>(bsum, SCAN_BLOCKS);
    scan3<<<(NROWS + 255) / 256, 256, 0, stream>>>(row_start, bsum);
    csr_fill<<<(NEDGES + 255) / 256, 256, 0, stream>>>(ei, row_start, cursor, bucket);

    const int gatherBlocks = (NROWS * 64) / 256;    // 75000
    const int gemmBlocks = (NN + 63) / 64;          // 1563

    // Layer 0
    gnn_gather<<<gatherBlocks, 256, 0, stream>>>(x, bucket, row_start, cnt, agg);
    gnn_gemm<1, 0><<<gemmBlocks, 256, 0, stream>>>(agg, x, Wn, Wr, b,
                                                   nullptr, nullptr, h1);

    // Layer 1 (+ fused classifier)
    gnn_gather<<<gatherBlocks, 256, 0, stream>>>(h1, bucket, row_start, cnt, agg);
    gnn_gemm<0, 1><<<gemmBlocks, 256, 0, stream>>>(agg, h1,
                                                   Wn + (size_t)NR * DD * DD,
                                                   Wr + (size_t)NR * DD * DD,
                                                   b + (size_t)NR * DD,
                                                   Wc, bc, out);
}

// Round 4
// 616.483 us; speedup vs baseline: 7.4517x; 1.4524x over previous
//
#include <hip/hip_runtime.h>

#define NN 100000
#define NE 400000
#define NR 3
#define DD 128
#define NROWS (NR * NN)
#define NEDGES (NR * NE)
#define SCAN_BLOCKS ((NROWS + 1023) / 1024)

typedef float f32x4 __attribute__((ext_vector_type(4)));
typedef __bf16 bf16x8 __attribute__((ext_vector_type(8)));

__device__ __forceinline__ unsigned short f2bf(float f) {
    unsigned int u = __float_as_uint(f);
    u += 0x7fff + ((u >> 16) & 1);          // round-to-nearest-even
    return (unsigned short)(u >> 16);
}

__device__ __forceinline__ void gload16(const void* g, void* l) {
    __builtin_amdgcn_global_load_lds(
        (const __attribute__((address_space(1))) void*)g,
        (__attribute__((address_space(3))) void*)l, 16, 0, 0);
}

// ---------- prep: x -> bf16 ----------
__global__ __launch_bounds__(256) void cvt_x(const float* __restrict__ x,
                                             unsigned short* __restrict__ xb) {
    int i = blockIdx.x * 256 + threadIdx.x;          // NN*DD/8 = 1.6M threads
    const float4* xf = reinterpret_cast<const float4*>(x + (size_t)i * 8);
    float4 a = xf[0], b = xf[1];
    uint4 o;
    o.x = (unsigned)f2bf(a.x) | ((unsigned)f2bf(a.y) << 16);
    o.y = (unsigned)f2bf(a.z) | ((unsigned)f2bf(a.w) << 16);
    o.z = (unsigned)f2bf(b.x) | ((unsigned)f2bf(b.y) << 16);
    o.w = (unsigned)f2bf(b.z) | ((unsigned)f2bf(b.w) << 16);
    reinterpret_cast<uint4*>(xb)[i] = o;
}

// ---------- prep: combined transposed weights Wt[l][n][k] (bf16), k in [0,512) ----------
__global__ __launch_bounds__(256) void prep_w(const float* __restrict__ Wn,
                                              const float* __restrict__ Wr,
                                              unsigned short* __restrict__ Wt) {
    int t = blockIdx.x * 256 + threadIdx.x;
    if (t >= 2 * 128 * 512) return;
    int l = t >> 16;
    int rem = t & 65535;
    int n = rem >> 9;
    int k = rem & 511;
    int rk = k >> 7, kk = k & 127;
    float v;
    if (rk < 3) {
        v = Wn[(((size_t)l * 3 + rk) * 128 + kk) * 128 + n];
    } else {
        const float* WrL = Wr + (size_t)l * 3 * 128 * 128;
        v = WrL[kk * 128 + n] + WrL[128 * 128 + kk * 128 + n] + WrL[2 * 128 * 128 + kk * 128 + n];
    }
    Wt[((size_t)l * 128 + n) * 512 + k] = f2bf(v);
}

__global__ __launch_bounds__(256) void prep_b(const float* __restrict__ b,
                                              float* __restrict__ bias) {
    int t = threadIdx.x;                              // 256 = 2 layers x 128
    int l = t >> 7, n = t & 127;
    bias[t] = b[l * 384 + n] + b[l * 384 + 128 + n] + b[l * 384 + 256 + n];
}

// ---------- CSR build ----------
__global__ __launch_bounds__(256) void csr_count(const int* __restrict__ ei,
                                                 int* __restrict__ cnt) {
    int t = blockIdx.x * 256 + threadIdx.x;
    if (t >= NEDGES) return;
    int r = t / NE;
    int e = t - r * NE;
    int dst = ei[(r * 2 + 1) * NE + e];
    atomicAdd(&cnt[r * NN + dst], 1);
}

__global__ __launch_bounds__(256) void scan1(const int* __restrict__ cnt,
                                             int* __restrict__ row_start,
                                             int* __restrict__ bsum) {
    __shared__ int sh[256];
    int b0 = blockIdx.x * 1024;
    int t = threadIdx.x;
    int v[4];
    int s = 0;
    #pragma unroll
    for (int j = 0; j < 4; ++j) {
        int idx = b0 + t * 4 + j;
        v[j] = (idx < NROWS) ? cnt[idx] : 0;
        s += v[j];
    }
    sh[t] = s;
    __syncthreads();
    for (int off = 1; off < 256; off <<= 1) {
        int val = (t >= off) ? sh[t - off] : 0;
        __syncthreads();
        sh[t] += val;
        __syncthreads();
    }
    int excl = (t == 0) ? 0 : sh[t - 1];
    if (t == 255) bsum[blockIdx.x] = sh[255];
    #pragma unroll
    for (int j = 0; j < 4; ++j) {
        int idx = b0 + t * 4 + j;
        if (idx < NROWS) { row_start[idx] = excl; excl += v[j]; }
    }
}

__global__ __launch_bounds__(512) void scan2(int* __restrict__ bsum, int nb) {
    __shared__ int sh[512];
    int t = threadIdx.x;
    sh[t] = (t < nb) ? bsum[t] : 0;
    __syncthreads();
    for (int off = 1; off < 512; off <<= 1) {
        int val = (t >= off) ? sh[t - off] : 0;
        __syncthreads();
        sh[t] += val;
        __syncthreads();
    }
    int excl = (t == 0) ? 0 : sh[t - 1];
    if (t < nb) bsum[t] = excl;
}

__global__ __launch_bounds__(256) void scan3(int* __restrict__ row_start,
                                             const int* __restrict__ bsum) {
    int idx = blockIdx.x * 256 + threadIdx.x;
    if (idx < NROWS) row_start[idx] += bsum[idx >> 10];
}

__global__ __launch_bounds__(256) void csr_fill(const int* __restrict__ ei,
                                                const int* __restrict__ row_start,
                                                int* __restrict__ cursor,
                                                int* __restrict__ bucket) {
    int t = blockIdx.x * 256 + threadIdx.x;
    if (t >= NEDGES) return;
    int r = t / NE;
    int e = t - r * NE;
    int src = ei[(r * 2 + 0) * NE + e];
    int dst = ei[(r * 2 + 1) * NE + e];
    int i = r * NN + dst;
    int pos = row_start[i] + atomicAdd(&cursor[i], 1);
    bucket[pos] = src;
}

// ---------- aggregation: one 64-lane wave per CSR row, bf16 in/out ----------
__global__ __launch_bounds__(256) void gnn_gather(const unsigned short* __restrict__ h,
                                                  const int* __restrict__ bucket,
                                                  const int* __restrict__ row_start,
                                                  const int* __restrict__ cnt,
                                                  unsigned short* __restrict__ agg) {
    int wid = (blockIdx.x * 256 + threadIdx.x) >> 6;
    int lane = threadIdx.x & 63;
    if (wid >= NROWS) return;
    int base = row_start[wid];
    int deg = cnt[wid];
    float a0 = 0.f, a1 = 0.f;
    for (int e = 0; e < deg; ++e) {
        int src = bucket[base + e];
        unsigned int v = reinterpret_cast<const unsigned int*>(h + (size_t)src * DD)[lane];
        a0 += __uint_as_float(v << 16);
        a1 += __uint_as_float(v & 0xffff0000u);
    }
    float sc = (deg > 0) ? (1.0f / (float)deg) : 0.0f;
    a0 *= sc; a1 *= sc;
    unsigned int o = (unsigned)f2bf(a0) | ((unsigned)f2bf(a1) << 16);
    reinterpret_cast<unsigned int*>(agg + (size_t)wid * DD)[lane] = o;
}

// ---------- MFMA GEMM: out[M,128] = [agg0|agg1|agg2|h] @ W (+bias, relu) ----------
// BM=128, BN=128, BK=32, 4 waves (2x2), each wave 64x64 = 4x4 frags of 16x16x32.
template <int RELU>
__global__ __launch_bounds__(256) void gemm_mfma(
    const unsigned short* __restrict__ aggb,  // [3*NN][128] bf16 (pre-divided means)
    const unsigned short* __restrict__ hb,    // [NN][128] bf16
    const unsigned short* __restrict__ Wt,    // [128 n][512 k] bf16 (transposed combined)
    const float* __restrict__ bias,           // [128]
    unsigned short* __restrict__ outb)        // [NN][128] bf16
{
    __shared__ __align__(16) unsigned short As[128 * 32];
    __shared__ __align__(16) unsigned short Bs[128 * 32];
    const int t = threadIdx.x;
    const int w = t >> 6, lane = t & 63;
    const int m0 = blockIdx.x * 128;
    const int wr = w >> 1, wc = w & 1;
    const int fr = lane & 15;        // fragment row/col
    const int fq = lane >> 4;        // k-group (x8) / row-group (x4)
    f32x4 acc[4][4] = {};

    #pragma unroll
    for (int s = 0; s < 16; ++s) {
        const int srcid = s >> 2;
        const int k0 = (s & 3) * 32;
        const unsigned short* Asrc = (srcid < 3) ? (aggb + (size_t)srcid * NN * DD) : hb;
        // stage A tile [128 rows][32 k] and B tile [128 n][32 k], 16B per lane per issue
        #pragma unroll
        for (int i = 0; i < 2; ++i) {
            int row = i * 64 + w * 16 + (lane >> 2);
            int grow = m0 + row;
            if (grow > NN - 1) grow = NN - 1;
            const unsigned short* gA = Asrc + (size_t)grow * DD + k0 + (lane & 3) * 8;
            gload16(gA, (char*)As + i * 4096 + w * 1024);
            // B global k = srcid*128 + k0 + local  (BUGFIX: srcid*128 was missing)
            const unsigned short* gB = Wt + (size_t)row * 512 + srcid * 128 + k0 + (lane & 3) * 8;
            gload16(gB, (char*)Bs + i * 4096 + w * 1024);
        }
        __syncthreads();
        bf16x8 af[4], bfr[4];
        #pragma unroll
        for (int m = 0; m < 4; ++m)
            af[m] = *reinterpret_cast<const bf16x8*>(As + (wr * 64 + m * 16 + fr) * 32 + fq * 8);
        #pragma unroll
        for (int n = 0; n < 4; ++n)
            bfr[n] = *reinterpret_cast<const bf16x8*>(Bs + (wc * 64 + n * 16 + fr) * 32 + fq * 8);
        #pragma unroll
        for (int m = 0; m < 4; ++m)
            #pragma unroll
            for (int n = 0; n < 4; ++n)
                acc[m][n] = __builtin_amdgcn_mfma_f32_16x16x32_bf16(af[m], bfr[n], acc[m][n], 0, 0, 0);
        __syncthreads();
    }

    // epilogue: C/D layout col=lane&15, row=(lane>>4)*4+j
    #pragma unroll
    for (int n = 0; n < 4; ++n) {
        int col = wc * 64 + n * 16 + fr;
        float bs = bias[col];
        #pragma unroll
        for (int m = 0; m < 4; ++m) {
            int rbase = m0 + wr * 64 + m * 16 + fq * 4;
            #pragma unroll
            for (int j = 0; j < 4; ++j) {
                int row = rbase + j;
                if (row < NN) {
                    float v = acc[m][n][j] + bs;
                    if (RELU) v = fmaxf(v, 0.f);
                    outb[(size_t)row * DD + col] = f2bf(v);
                }
            }
        }
    }
}

// ---------- classifier: one wave per node row ----------
__global__ __launch_bounds__(256) void classify(const unsigned short* __restrict__ h2,
                                                const float* __restrict__ Wc,
                                                const float* __restrict__ bc,
                                                float* __restrict__ out) {
    int wid = (blockIdx.x * 256 + threadIdx.x) >> 6;
    int lane = threadIdx.x & 63;
    if (wid >= NN) return;
    float4 wc4 = reinterpret_cast<const float4*>(Wc)[lane];   // Wc[2l][0..1], Wc[2l+1][0..1]
    unsigned int v = reinterpret_cast<const unsigned int*>(h2 + (size_t)wid * DD)[lane];
    float v0 = __uint_as_float(v << 16);
    float v1 = __uint_as_float(v & 0xffff0000u);
    float p0 = v0 * wc4.x + v1 * wc4.z;
    float p1 = v0 * wc4.y + v1 * wc4.w;
    #pragma unroll
    for (int off = 1; off < 64; off <<= 1) {
        p0 += __shfl_xor(p0, off);
        p1 += __shfl_xor(p1, off);
    }
    if (lane == 0) {
        out[(size_t)wid * 2 + 0] = p0 + bc[0];
        out[(size_t)wid * 2 + 1] = p1 + bc[1];
    }
}

extern "C" void kernel_launch(void* const* d_in, const int* in_sizes, int n_in,
                              void* d_out, int out_size, void* d_ws, size_t ws_size,
                              hipStream_t stream) {
    const float* x  = (const float*)d_in[0];
    const int*   ei = (const int*)d_in[1];
    const float* Wn = (const float*)d_in[2];
    const float* Wr = (const float*)d_in[3];
    const float* b  = (const float*)d_in[4];
    const float* Wc = (const float*)d_in[5];
    const float* bc = (const float*)d_in[6];
    float* out = (float*)d_out;

    char* p = (char*)d_ws;
    unsigned short* aggb = (unsigned short*)p;  p += (size_t)NR * NN * DD * 2;
    unsigned short* xb   = (unsigned short*)p;  p += (size_t)NN * DD * 2;
    unsigned short* h1b  = (unsigned short*)p;  p += (size_t)NN * DD * 2;
    unsigned short* h2b  = (unsigned short*)p;  p += (size_t)NN * DD * 2;
    unsigned short* Wt   = (unsigned short*)p;  p += (size_t)2 * 128 * 512 * 2;
    float* bias          = (float*)p;           p += 2 * 128 * 4;
    int* bucket          = (int*)p;             p += (size_t)NEDGES * 4;
    int* cnt             = (int*)p;             p += (size_t)NROWS * 4;
    int* row_start       = (int*)p;             p += (size_t)NROWS * 4;
    int* cursor          = (int*)p;             p += (size_t)NROWS * 4;
    int* bsum            = (int*)p;             p += 512 * 4;

    hipMemsetAsync(cnt, 0, NROWS * sizeof(int), stream);
    hipMemsetAsync(cursor, 0, NROWS * sizeof(int), stream);

    // CSR build (shared by both layers)
    csr_count<<<(NEDGES + 255) / 256, 256, 0, stream>>>(ei, cnt);
    scan1<<<SCAN_BLOCKS, 256, 0, stream>>>(cnt, row_start, bsum);
    scan2<<<1, 512, 0, stream>>>(bsum, SCAN_BLOCKS);
    scan3<<<(NROWS + 255) / 256, 256, 0, stream>>>(row_start, bsum);
    csr_fill<<<(NEDGES + 255) / 256, 256, 0, stream>>>(ei, row_start, cursor, bucket);

    // prep
    cvt_x<<<(NN * DD / 8 + 255) / 256, 256, 0, stream>>>(x, xb);
    prep_w<<<(2 * 128 * 512 + 255) / 256, 256, 0, stream>>>(Wn, Wr, Wt);
    prep_b<<<1, 256, 0, stream>>>(b, bias);

    const int gatherBlocks = (NROWS * 64) / 256;     // 75000
    const int gemmBlocks = (NN + 127) / 128;         // 782

    // Layer 0
    gnn_gather<<<gatherBlocks, 256, 0, stream>>>(xb, bucket, row_start, cnt, aggb);
    gemm_mfma<1><<<gemmBlocks, 256, 0, stream>>>(aggb, xb, Wt, bias, h1b);

    // Layer 1
    gnn_gather<<<gatherBlocks, 256, 0, stream>>>(h1b, bucket, row_start, cnt, aggb);
    gemm_mfma<0><<<gemmBlocks, 256, 0, stream>>>(aggb, h1b, Wt + (size_t)128 * 512,
                                                 bias + 128, h2b);

    // Classifier
    classify<<<(NN * 64 + 255) / 256, 256, 0, stream>>>(h2b, Wc, bc, out);
}

// Round 5
// 518.190 us; speedup vs baseline: 8.8652x; 1.1897x over previous
//
#include <hip/hip_runtime.h>

#define NN 100000
#define NE 400000
#define NR 3
#define DD 128
#define NROWS (NR * NN)
#define NEDGES (NR * NE)
#define SCAN_BLOCKS ((NROWS + 1023) / 1024)

typedef float f32x4 __attribute__((ext_vector_type(4)));
typedef __bf16 bf16x8 __attribute__((ext_vector_type(8)));

__device__ __forceinline__ unsigned short f2bf(float f) {
    unsigned int u = __float_as_uint(f);
    u += 0x7fff + ((u >> 16) & 1);          // round-to-nearest-even
    return (unsigned short)(u >> 16);
}

__device__ __forceinline__ void gload16(const void* g, void* l) {
    __builtin_amdgcn_global_load_lds(
        (const __attribute__((address_space(1))) void*)g,
        (__attribute__((address_space(3))) void*)l, 16, 0, 0);
}

// ---------- prep: x -> bf16 ----------
__global__ __launch_bounds__(256) void cvt_x(const float* __restrict__ x,
                                             unsigned short* __restrict__ xb) {
    int i = blockIdx.x * 256 + threadIdx.x;          // NN*DD/8 = 1.6M threads
    const float4* xf = reinterpret_cast<const float4*>(x + (size_t)i * 8);
    float4 a = xf[0], b = xf[1];
    uint4 o;
    o.x = (unsigned)f2bf(a.x) | ((unsigned)f2bf(a.y) << 16);
    o.y = (unsigned)f2bf(a.z) | ((unsigned)f2bf(a.w) << 16);
    o.z = (unsigned)f2bf(b.x) | ((unsigned)f2bf(b.y) << 16);
    o.w = (unsigned)f2bf(b.z) | ((unsigned)f2bf(b.w) << 16);
    reinterpret_cast<uint4*>(xb)[i] = o;
}

// ---------- prep: combined transposed weights Wt[l][n][k] (bf16), k in [0,512) ----------
__global__ __launch_bounds__(256) void prep_w(const float* __restrict__ Wn,
                                              const float* __restrict__ Wr,
                                              unsigned short* __restrict__ Wt) {
    int t = blockIdx.x * 256 + threadIdx.x;
    if (t >= 2 * 128 * 512) return;
    int l = t >> 16;
    int rem = t & 65535;
    int n = rem >> 9;
    int k = rem & 511;
    int rk = k >> 7, kk = k & 127;
    float v;
    if (rk < 3) {
        v = Wn[(((size_t)l * 3 + rk) * 128 + kk) * 128 + n];
    } else {
        const float* WrL = Wr + (size_t)l * 3 * 128 * 128;
        v = WrL[kk * 128 + n] + WrL[128 * 128 + kk * 128 + n] + WrL[2 * 128 * 128 + kk * 128 + n];
    }
    Wt[((size_t)l * 128 + n) * 512 + k] = f2bf(v);
}

__global__ __launch_bounds__(256) void prep_b(const float* __restrict__ b,
                                              float* __restrict__ bias) {
    int t = threadIdx.x;                              // 256 = 2 layers x 128
    int l = t >> 7, n = t & 127;
    bias[t] = b[l * 384 + n] + b[l * 384 + 128 + n] + b[l * 384 + 256 + n];
}

// ---------- CSR build ----------
__global__ __launch_bounds__(256) void csr_count(const int* __restrict__ ei,
                                                 int* __restrict__ cnt) {
    int t = blockIdx.x * 256 + threadIdx.x;
    if (t >= NEDGES) return;
    int r = t / NE;
    int e = t - r * NE;
    int dst = ei[(r * 2 + 1) * NE + e];
    atomicAdd(&cnt[r * NN + dst], 1);
}

__global__ __launch_bounds__(256) void scan1(const int* __restrict__ cnt,
                                             int* __restrict__ row_start,
                                             int* __restrict__ bsum) {
    __shared__ int sh[256];
    int b0 = blockIdx.x * 1024;
    int t = threadIdx.x;
    int v[4];
    int s = 0;
    #pragma unroll
    for (int j = 0; j < 4; ++j) {
        int idx = b0 + t * 4 + j;
        v[j] = (idx < NROWS) ? cnt[idx] : 0;
        s += v[j];
    }
    sh[t] = s;
    __syncthreads();
    for (int off = 1; off < 256; off <<= 1) {
        int val = (t >= off) ? sh[t - off] : 0;
        __syncthreads();
        sh[t] += val;
        __syncthreads();
    }
    int excl = (t == 0) ? 0 : sh[t - 1];
    if (t == 255) bsum[blockIdx.x] = sh[255];
    #pragma unroll
    for (int j = 0; j < 4; ++j) {
        int idx = b0 + t * 4 + j;
        if (idx < NROWS) { row_start[idx] = excl; excl += v[j]; }
    }
}

__global__ __launch_bounds__(512) void scan2(int* __restrict__ bsum, int nb) {
    __shared__ int sh[512];
    int t = threadIdx.x;
    sh[t] = (t < nb) ? bsum[t] : 0;
    __syncthreads();
    for (int off = 1; off < 512; off <<= 1) {
        int val = (t >= off) ? sh[t - off] : 0;
        __syncthreads();
        sh[t] += val;
        __syncthreads();
    }
    int excl = (t == 0) ? 0 : sh[t - 1];
    if (t < nb) bsum[t] = excl;
}

__global__ __launch_bounds__(256) void scan3(int* __restrict__ row_start,
                                             const int* __restrict__ bsum) {
    int idx = blockIdx.x * 256 + threadIdx.x;
    if (idx < NROWS) row_start[idx] += bsum[idx >> 10];
}

__global__ __launch_bounds__(256) void csr_fill(const int* __restrict__ ei,
                                                const int* __restrict__ row_start,
                                                int* __restrict__ cursor,
                                                int* __restrict__ bucket) {
    int t = blockIdx.x * 256 + threadIdx.x;
    if (t >= NEDGES) return;
    int r = t / NE;
    int e = t - r * NE;
    int src = ei[(r * 2 + 0) * NE + e];
    int dst = ei[(r * 2 + 1) * NE + e];
    int i = r * NN + dst;
    int pos = row_start[i] + atomicAdd(&cursor[i], 1);
    bucket[pos] = src;
}

// ---------- aggregation: one 64-lane wave per CSR row, 4-wide ILP unroll ----------
__global__ __launch_bounds__(256) void gnn_gather(const unsigned short* __restrict__ h,
                                                  const int* __restrict__ bucket,
                                                  const int* __restrict__ row_start,
                                                  const int* __restrict__ cnt,
                                                  unsigned short* __restrict__ agg) {
    int wid = (blockIdx.x * 256 + threadIdx.x) >> 6;
    int lane = threadIdx.x & 63;
    if (wid >= NROWS) return;
    int base = row_start[wid];
    int deg = cnt[wid];
    const unsigned int* hw = reinterpret_cast<const unsigned int*>(h);
    float a0 = 0.f, a1 = 0.f, b0 = 0.f, b1 = 0.f;
    float c0 = 0.f, c1 = 0.f, d0 = 0.f, d1 = 0.f;
    int e = 0;
    for (; e + 4 <= deg; e += 4) {
        int s0 = bucket[base + e + 0];
        int s1 = bucket[base + e + 1];
        int s2 = bucket[base + e + 2];
        int s3 = bucket[base + e + 3];
        unsigned int v0 = hw[(size_t)s0 * 64 + lane];
        unsigned int v1 = hw[(size_t)s1 * 64 + lane];
        unsigned int v2 = hw[(size_t)s2 * 64 + lane];
        unsigned int v3 = hw[(size_t)s3 * 64 + lane];
        a0 += __uint_as_float(v0 << 16); a1 += __uint_as_float(v0 & 0xffff0000u);
        b0 += __uint_as_float(v1 << 16); b1 += __uint_as_float(v1 & 0xffff0000u);
        c0 += __uint_as_float(v2 << 16); c1 += __uint_as_float(v2 & 0xffff0000u);
        d0 += __uint_as_float(v3 << 16); d1 += __uint_as_float(v3 & 0xffff0000u);
    }
    for (; e < deg; ++e) {
        int s0 = bucket[base + e];
        unsigned int v0 = hw[(size_t)s0 * 64 + lane];
        a0 += __uint_as_float(v0 << 16); a1 += __uint_as_float(v0 & 0xffff0000u);
    }
    a0 = (a0 + b0) + (c0 + d0);
    a1 = (a1 + b1) + (c1 + d1);
    float sc = (deg > 0) ? (1.0f / (float)deg) : 0.0f;
    a0 *= sc; a1 *= sc;
    unsigned int o = (unsigned)f2bf(a0) | ((unsigned)f2bf(a1) << 16);
    reinterpret_cast<unsigned int*>(agg + (size_t)wid * DD)[lane] = o;
}

// ---------- MFMA GEMM: out[M,128] = [agg0|agg1|agg2|h] @ W (+bias, relu) ----------
// BM=128, BN=128, BK=32, 4 waves (2x2), 2-phase double-buffered staging (T3 minimum).
template <int RELU>
__global__ __launch_bounds__(256) void gemm_mfma(
    const unsigned short* __restrict__ aggb,  // [3*NN][128] bf16 (pre-divided means)
    const unsigned short* __restrict__ hb,    // [NN][128] bf16
    const unsigned short* __restrict__ Wt,    // [128 n][512 k] bf16 (transposed combined)
    const float* __restrict__ bias,           // [128]
    unsigned short* __restrict__ outb)        // [NN][128] bf16
{
    __shared__ __align__(16) unsigned short As[2 * 128 * 32];
    __shared__ __align__(16) unsigned short Bs[2 * 128 * 32];
    const int t = threadIdx.x;
    const int w = t >> 6, lane = t & 63;
    const int m0 = blockIdx.x * 128;
    const int wr = w >> 1, wc = w & 1;
    const int fr = lane & 15;        // fragment row/col
    const int fq = lane >> 4;        // k-group (x8) / row-group (x4)
    f32x4 acc[4][4] = {};

    auto stage = [&](int s, int buf) {
        const int srcid = s >> 2;
        const int k0 = (s & 3) * 32;
        const unsigned short* Asrc = (srcid < 3) ? (aggb + (size_t)srcid * NN * DD) : hb;
        #pragma unroll
        for (int i = 0; i < 2; ++i) {
            int row = i * 64 + w * 16 + (lane >> 2);
            int grow = m0 + row;
            if (grow > NN - 1) grow = NN - 1;
            const unsigned short* gA = Asrc + (size_t)grow * DD + k0 + (lane & 3) * 8;
            gload16(gA, (char*)As + buf * 8192 + i * 4096 + w * 1024);
            const unsigned short* gB = Wt + (size_t)row * 512 + srcid * 128 + k0 + (lane & 3) * 8;
            gload16(gB, (char*)Bs + buf * 8192 + i * 4096 + w * 1024);
        }
    };

    stage(0, 0);
    #pragma unroll
    for (int s = 0; s < 16; ++s) {
        const int cur = s & 1;
        __syncthreads();                       // vmcnt drain -> buf[cur] ready
        if (s + 1 < 16) stage(s + 1, cur ^ 1); // prefetch overlaps MFMA below
        bf16x8 af[4], bfr[4];
        #pragma unroll
        for (int m = 0; m < 4; ++m)
            af[m] = *reinterpret_cast<const bf16x8*>(As + cur * 4096 + (wr * 64 + m * 16 + fr) * 32 + fq * 8);
        #pragma unroll
        for (int n = 0; n < 4; ++n)
            bfr[n] = *reinterpret_cast<const bf16x8*>(Bs + cur * 4096 + (wc * 64 + n * 16 + fr) * 32 + fq * 8);
        #pragma unroll
        for (int m = 0; m < 4; ++m)
            #pragma unroll
            for (int n = 0; n < 4; ++n)
                acc[m][n] = __builtin_amdgcn_mfma_f32_16x16x32_bf16(af[m], bfr[n], acc[m][n], 0, 0, 0);
    }

    // epilogue: C/D layout col=lane&15, row=(lane>>4)*4+j
    #pragma unroll
    for (int n = 0; n < 4; ++n) {
        int col = wc * 64 + n * 16 + fr;
        float bs = bias[col];
        #pragma unroll
        for (int m = 0; m < 4; ++m) {
            int rbase = m0 + wr * 64 + m * 16 + fq * 4;
            #pragma unroll
            for (int j = 0; j < 4; ++j) {
                int row = rbase + j;
                if (row < NN) {
                    float v = acc[m][n][j] + bs;
                    if (RELU) v = fmaxf(v, 0.f);
                    outb[(size_t)row * DD + col] = f2bf(v);
                }
            }
        }
    }
}

// ---------- classifier: one wave per node row ----------
__global__ __launch_bounds__(256) void classify(const unsigned short* __restrict__ h2,
                                                const float* __restrict__ Wc,
                                                const float* __restrict__ bc,
                                                float* __restrict__ out) {
    int wid = (blockIdx.x * 256 + threadIdx.x) >> 6;
    int lane = threadIdx.x & 63;
    if (wid >= NN) return;
    float4 wc4 = reinterpret_cast<const float4*>(Wc)[lane];   // Wc[2l][0..1], Wc[2l+1][0..1]
    unsigned int v = reinterpret_cast<const unsigned int*>(h2 + (size_t)wid * DD)[lane];
    float v0 = __uint_as_float(v << 16);
    float v1 = __uint_as_float(v & 0xffff0000u);
    float p0 = v0 * wc4.x + v1 * wc4.z;
    float p1 = v0 * wc4.y + v1 * wc4.w;
    #pragma unroll
    for (int off = 1; off < 64; off <<= 1) {
        p0 += __shfl_xor(p0, off);
        p1 += __shfl_xor(p1, off);
    }
    if (lane == 0) {
        out[(size_t)wid * 2 + 0] = p0 + bc[0];
        out[(size_t)wid * 2 + 1] = p1 + bc[1];
    }
}

extern "C" void kernel_launch(void* const* d_in, const int* in_sizes, int n_in,
                              void* d_out, int out_size, void* d_ws, size_t ws_size,
                              hipStream_t stream) {
    const float* x  = (const float*)d_in[0];
    const int*   ei = (const int*)d_in[1];
    const float* Wn = (const float*)d_in[2];
    const float* Wr = (const float*)d_in[3];
    const float* b  = (const float*)d_in[4];
    const float* Wc = (const float*)d_in[5];
    const float* bc = (const float*)d_in[6];
    float* out = (float*)d_out;

    char* p = (char*)d_ws;
    unsigned short* aggb = (unsigned short*)p;  p += (size_t)NR * NN * DD * 2;
    unsigned short* xb   = (unsigned short*)p;  p += (size_t)NN * DD * 2;
    unsigned short* h1b  = (unsigned short*)p;  p += (size_t)NN * DD * 2;
    unsigned short* h2b  = (unsigned short*)p;  p += (size_t)NN * DD * 2;
    unsigned short* Wt   = (unsigned short*)p;  p += (size_t)2 * 128 * 512 * 2;
    float* bias          = (float*)p;           p += 2 * 128 * 4;
    int* bucket          = (int*)p;             p += (size_t)NEDGES * 4;
    int* cnt             = (int*)p;             p += (size_t)NROWS * 4;
    int* row_start       = (int*)p;             p += (size_t)NROWS * 4;
    int* cursor          = (int*)p;             p += (size_t)NROWS * 4;
    int* bsum            = (int*)p;             p += 512 * 4;

    hipMemsetAsync(cnt, 0, NROWS * sizeof(int), stream);
    hipMemsetAsync(cursor, 0, NROWS * sizeof(int), stream);

    // CSR build (shared by both layers)
    csr_count<<<(NEDGES + 255) / 256, 256, 0, stream>>>(ei, cnt);
    scan1<<<SCAN_BLOCKS, 256, 0, stream>>>(cnt, row_start, bsum);
    scan2<<<1, 512, 0, stream>>>(bsum, SCAN_BLOCKS);
    scan3<<<(NROWS + 255) / 256, 256, 0, stream>>>(row_start, bsum);
    csr_fill<<<(NEDGES + 255) / 256, 256, 0, stream>>>(ei, row_start, cursor, bucket);

    // prep
    cvt_x<<<(NN * DD / 8 + 255) / 256, 256, 0, stream>>>(x, xb);
    prep_w<<<(2 * 128 * 512 + 255) / 256, 256, 0, stream>>>(Wn, Wr, Wt);
    prep_b<<<1, 256, 0, stream>>>(b, bias);

    const int gatherBlocks = (NROWS * 64) / 256;     // 75000
    const int gemmBlocks = (NN + 127) / 128;         // 782

    // Layer 0
    gnn_gather<<<gatherBlocks, 256, 0, stream>>>(xb, bucket, row_start, cnt, aggb);
    gemm_mfma<1><<<gemmBlocks, 256, 0, stream>>>(aggb, xb, Wt, bias, h1b);

    // Layer 1
    gnn_gather<<<gatherBlocks, 256, 0, stream>>>(h1b, bucket, row_start, cnt, aggb);
    gemm_mfma<0><<<gemmBlocks, 256, 0, stream>>>(aggb, h1b, Wt + (size_t)128 * 512,
                                                 bias + 128, h2b);

    // Classifier
    classify<<<(NN * 64 + 255) / 256, 256, 0, stream>>>(h2b, Wc, bc, out);
}